// Round 3
// baseline (436.613 us; speedup 1.0000x reference)
//
#include <hip/hip_runtime.h>

typedef __attribute__((ext_vector_type(8))) short short8_t;
typedef __attribute__((ext_vector_type(4))) float f32x4;

#define MASK_VAL (-4294967295.0f)

__device__ __forceinline__ short f2bf(float x) {
    unsigned u;
    __builtin_memcpy(&u, &x, 4);
    u += 0x7FFFu + ((u >> 16) & 1u);   // round-to-nearest-even
    return (short)(u >> 16);
}

// ---------------- prep: fold weights into d_ws (runs every call) ----------------
// ws layout (bytes):
//   0     : wkT  bf16 [64][64]  (W1b - W1c)^T   (row n, col k)
//   8192  : wdT  bf16 [64][64]  (W1d)^T
//   16384 : w2T  bf16 [32][64]  (W2)^T          (row o, col h)
//   20480 : wac  f32  [64][64]  W1a + W1c       (row i, col h)
// total 36864 B
__global__ void prep_fold(const float* __restrict__ W1, const float* __restrict__ W2,
                          void* __restrict__ ws)
{
    short* wkT = (short*)ws;
    short* wdT = wkT + 4096;
    short* w2T = wkT + 8192;
    float* wac = (float*)((char*)ws + 20480);
    const int tid = threadIdx.x;
    for (int idx = tid; idx < 4096; idx += 256) {
        int n = idx & 63, k = idx >> 6;
        float a  = W1[4096  + idx];   // W1b[k][n]
        float c  = W1[8192  + idx];   // W1c[k][n]
        float d  = W1[12288 + idx];   // W1d[k][n]
        wkT[n * 64 + k] = f2bf(a - c);
        wdT[n * 64 + k] = f2bf(d);
        wac[idx] = W1[idx] + c;       // elementwise: W1a + W1c (i-major)
    }
    for (int idx = tid; idx < 2048; idx += 256) {
        int o = idx & 31, h = idx >> 5;
        w2T[o * 64 + h] = f2bf(W2[idx]);   // W2[h][o], idx = h*32+o
    }
}

// ---------------- main: one block per batch ----------------
// h1[t,h] = relu( k[t]@(W1b-W1c) + (k[t]*q)@W1d + c )   (K=64 MFMA, two B-mats)
// c[h]    = q@(W1a+W1c)[.,h] + b1[h]
// s[t]    = relu(h1@W2 + b2) @ W3 + b3 ; masked softmax ; out = w @ keys (fp32)
__global__ __launch_bounds__(256, 4) void attn_main(
    const float* __restrict__ query,    // (B,1,64)
    const float* __restrict__ keys,     // (B,200,64)
    const int*   __restrict__ keys_len, // (B,1)
    const float* __restrict__ b1,       // (64)
    const float* __restrict__ b2,       // (32)
    const float* __restrict__ W3,       // (32,1)
    const float* __restrict__ b3,       // (1)
    const void*  __restrict__ ws,
    float* __restrict__ out)            // (B,1,64)
{
    constexpr int STR = 72;   // shorts; 144 B row stride -> 16B-aligned b128 everywhere
    const short* wkT = (const short*)ws;
    const short* wdT = wkT + 4096;
    const short* w2T = wkT + 8192;
    const float* wac = (const float*)((const char*)ws + 20480);

    __shared__ short Bk[64 * STR];      // (W1b-W1c)^T
    __shared__ short Bd[64 * STR];      // W1d^T
    __shared__ short W2s[32 * STR];     // W2^T
    __shared__ short h1w[4][16 * STR];  // per-wave h1 tile (C-layout -> A-layout)
    __shared__ float qs[64], cs[64], b2s[32], w3s[32];
    __shared__ float s_arr[208], wsm[208];
    __shared__ float red[1024];
    __shared__ float red4a[4], red4b[4];

    const int b    = blockIdx.x;
    const int tid  = threadIdx.x;
    const int lane = tid & 63;
    const int wid  = tid >> 6;
    const int col  = lane & 15;
    const int quad = lane >> 4;

    // ---- stage q + folded B-matrices (global, L2/L3-hot) ----
    if (tid < 16) ((float4*)qs)[tid] = ((const float4*)(query + (size_t)b * 64))[tid];
    // Bk/Bd: 64x64 shorts = 512 chunks of short8; 2 chunks per thread
    for (int c = tid; c < 512; c += 256) {
        int r = c >> 3, ch = (c & 7) * 8;
        *(short8_t*)&Bk[r * STR + ch] = *(const short8_t*)(wkT + r * 64 + ch);
        *(short8_t*)&Bd[r * STR + ch] = *(const short8_t*)(wdT + r * 64 + ch);
    }
    // W2s: 32x64 shorts = 256 chunks; 1 per thread
    {
        int r = tid >> 3, ch = (tid & 7) * 8;
        *(short8_t*)&W2s[r * STR + ch] = *(const short8_t*)(w2T + r * 64 + ch);
    }
    if (tid < 32) { b2s[tid] = b2[tid]; w3s[tid] = W3[tid]; }
    __syncthreads();   // qs + LDS matrices ready

    // ---- c_b partials: all 256 threads, 16 MACs each ----
    {
        int g = tid >> 6, h = tid & 63;
        float acc = 0.f;
#pragma unroll
        for (int j = 0; j < 16; ++j) {
            int i = g * 16 + j;
            acc += qs[i] * wac[i * 64 + h];
        }
        red[tid] = acc;
    }
    // per-lane q fragments for the (k*q) A-operand (qs is stable now)
    float4 qv[4];
#pragma unroll
    for (int ks = 0; ks < 2; ++ks) {
        qv[ks * 2]     = *(const float4*)&qs[ks * 32 + quad * 8];
        qv[ks * 2 + 1] = *(const float4*)&qs[ks * 32 + quad * 8 + 4];
    }
    __syncthreads();   // red ready
    if (tid < 64)
        cs[tid] = b1[tid] + red[tid] + red[64 + tid] + red[128 + tid] + red[192 + tid];
    __syncthreads();   // cs ready

    // ---- main wave loop: GEMM1 (global->reg A-frags) + fused GEMM2 -> s[t] ----
    const float  b3v = b3[0];
    const float* kb  = keys + (size_t)b * 12800;
    short* hw = h1w[wid];

    for (int mt = wid; mt < 13; mt += 4) {
        int row = mt * 16 + col;
        row = row < 200 ? row : 199;                 // tail clamp (in-bounds read)
        const float* kr = kb + row * 64 + quad * 8;
        float4 k0 = *(const float4*)(kr);
        float4 k1 = *(const float4*)(kr + 4);
        float4 k2 = *(const float4*)(kr + 32);
        float4 k3 = *(const float4*)(kr + 36);

        short8_t aK0, aK1, aQ0, aQ1;
        aK0[0] = f2bf(k0.x); aK0[1] = f2bf(k0.y); aK0[2] = f2bf(k0.z); aK0[3] = f2bf(k0.w);
        aK0[4] = f2bf(k1.x); aK0[5] = f2bf(k1.y); aK0[6] = f2bf(k1.z); aK0[7] = f2bf(k1.w);
        aK1[0] = f2bf(k2.x); aK1[1] = f2bf(k2.y); aK1[2] = f2bf(k2.z); aK1[3] = f2bf(k2.w);
        aK1[4] = f2bf(k3.x); aK1[5] = f2bf(k3.y); aK1[6] = f2bf(k3.z); aK1[7] = f2bf(k3.w);
        aQ0[0] = f2bf(k0.x * qv[0].x); aQ0[1] = f2bf(k0.y * qv[0].y);
        aQ0[2] = f2bf(k0.z * qv[0].z); aQ0[3] = f2bf(k0.w * qv[0].w);
        aQ0[4] = f2bf(k1.x * qv[1].x); aQ0[5] = f2bf(k1.y * qv[1].y);
        aQ0[6] = f2bf(k1.z * qv[1].z); aQ0[7] = f2bf(k1.w * qv[1].w);
        aQ1[0] = f2bf(k2.x * qv[2].x); aQ1[1] = f2bf(k2.y * qv[2].y);
        aQ1[2] = f2bf(k2.z * qv[2].z); aQ1[3] = f2bf(k2.w * qv[2].w);
        aQ1[4] = f2bf(k3.x * qv[3].x); aQ1[5] = f2bf(k3.y * qv[3].y);
        aQ1[6] = f2bf(k3.z * qv[3].z); aQ1[7] = f2bf(k3.w * qv[3].w);

        f32x4 acc[4] = {f32x4{0,0,0,0}, f32x4{0,0,0,0}, f32x4{0,0,0,0}, f32x4{0,0,0,0}};
#pragma unroll
        for (int nt = 0; nt < 4; ++nt) {
            const short* bp = &Bk[(nt * 16 + col) * STR + quad * 8];
            const short* dp = &Bd[(nt * 16 + col) * STR + quad * 8];
            acc[nt] = __builtin_amdgcn_mfma_f32_16x16x32_bf16(aK0, *(const short8_t*)bp,        acc[nt], 0, 0, 0);
            acc[nt] = __builtin_amdgcn_mfma_f32_16x16x32_bf16(aK1, *(const short8_t*)(bp + 32), acc[nt], 0, 0, 0);
            acc[nt] = __builtin_amdgcn_mfma_f32_16x16x32_bf16(aQ0, *(const short8_t*)dp,        acc[nt], 0, 0, 0);
            acc[nt] = __builtin_amdgcn_mfma_f32_16x16x32_bf16(aQ1, *(const short8_t*)(dp + 32), acc[nt], 0, 0, 0);
        }

        // relu + c -> per-wave h1 tile (C-layout scatter; intra-wave LDS is in-order)
#pragma unroll
        for (int nt = 0; nt < 4; ++nt) {
            float cadd = cs[nt * 16 + col];
#pragma unroll
            for (int r = 0; r < 4; ++r)
                hw[(quad * 4 + r) * STR + nt * 16 + col] = f2bf(fmaxf(acc[nt][r] + cadd, 0.f));
        }

        // GEMM2 (K=64) + fused b2/relu/W3/b3 -> s[t]
        f32x4 acc2[2] = {f32x4{0,0,0,0}, f32x4{0,0,0,0}};
#pragma unroll
        for (int ks = 0; ks < 2; ++ks) {
            short8_t a2 = *(const short8_t*)&hw[col * STR + ks * 32 + quad * 8];
            acc2[0] = __builtin_amdgcn_mfma_f32_16x16x32_bf16(
                a2, *(const short8_t*)&W2s[col * STR + ks * 32 + quad * 8], acc2[0], 0, 0, 0);
            acc2[1] = __builtin_amdgcn_mfma_f32_16x16x32_bf16(
                a2, *(const short8_t*)&W2s[(16 + col) * STR + ks * 32 + quad * 8], acc2[1], 0, 0, 0);
        }
#pragma unroll
        for (int r = 0; r < 4; ++r) {
            float v = fmaxf(acc2[0][r] + b2s[col], 0.f) * w3s[col]
                    + fmaxf(acc2[1][r] + b2s[16 + col], 0.f) * w3s[16 + col];
            v += __shfl_xor(v, 1);
            v += __shfl_xor(v, 2);
            v += __shfl_xor(v, 4);
            v += __shfl_xor(v, 8);
            if (col == 0) s_arr[mt * 16 + quad * 4 + r] = v + b3v;
        }
    }
    __syncthreads();

    // ---- masked softmax (len==0 -> uniform, matches reference) ----
    int len = keys_len[b];
    float val = (tid < 200) ? ((tid < len) ? s_arr[tid] : MASK_VAL) : -INFINITY;
    float m = val;
    for (int off = 32; off >= 1; off >>= 1) m = fmaxf(m, __shfl_xor(m, off));
    if (lane == 0) red4a[wid] = m;
    __syncthreads();
    m = fmaxf(fmaxf(red4a[0], red4a[1]), fmaxf(red4a[2], red4a[3]));
    float p = (tid < 200) ? __expf(val - m) : 0.0f;
    float ssum = p;
    for (int off = 32; off >= 1; off >>= 1) ssum += __shfl_xor(ssum, off);
    if (lane == 0) red4b[wid] = ssum;
    __syncthreads();
    float S = red4b[0] + red4b[1] + red4b[2] + red4b[3];
    if (tid < 200) wsm[tid] = p / S;
    __syncthreads();

    // ---- out = w @ keys, fp32 from global (L2-hot re-read), float4 per lane ----
    {
        int e4 = (tid & 15) * 4, g = tid >> 4;
        float ax = 0.f, ay = 0.f, az = 0.f, aw = 0.f;
        for (int t = g; t < 200; t += 16) {
            float w = wsm[t];
            float4 kv = *(const float4*)(kb + t * 64 + e4);
            ax += w * kv.x; ay += w * kv.y; az += w * kv.z; aw += w * kv.w;
        }
        float4 r4 = {ax, ay, az, aw};
        *(float4*)&red[g * 64 + e4] = r4;
        __syncthreads();
        if (tid < 64) {
            float s = 0.f;
#pragma unroll
            for (int g2 = 0; g2 < 16; ++g2) s += red[g2 * 64 + tid];
            out[(size_t)b * 64 + tid] = s;
        }
    }
}

extern "C" void kernel_launch(void* const* d_in, const int* in_sizes, int n_in,
                              void* d_out, int out_size, void* d_ws, size_t ws_size,
                              hipStream_t stream) {
    const float* query    = (const float*)d_in[0];
    const float* keys     = (const float*)d_in[1];
    const int*   keys_len = (const int*)d_in[2];
    const float* W1       = (const float*)d_in[3];
    const float* b1       = (const float*)d_in[4];
    const float* W2       = (const float*)d_in[5];
    const float* b2       = (const float*)d_in[6];
    const float* W3       = (const float*)d_in[7];
    const float* b3       = (const float*)d_in[8];
    float* out            = (float*)d_out;

    const int B = in_sizes[1] / 12800;   // keys is (B,200,64)

    prep_fold<<<dim3(1), dim3(256), 0, stream>>>(W1, W2, d_ws);
    attn_main<<<dim3(B), dim3(256), 0, stream>>>(
        query, keys, keys_len, b1, b2, W3, b3, d_ws, out);
}

// Round 4
// 330.398 us; speedup vs baseline: 1.3215x; 1.3215x over previous
//
#include <hip/hip_runtime.h>

typedef __attribute__((ext_vector_type(8))) short short8_t;
typedef __attribute__((ext_vector_type(4))) float f32x4;

#define MASK_VAL (-4294967295.0f)

__device__ __forceinline__ short f2bf(float x) {
    unsigned u;
    __builtin_memcpy(&u, &x, 4);
    u += 0x7FFFu + ((u >> 16) & 1u);   // round-to-nearest-even
    return (short)(u >> 16);
}
__device__ __forceinline__ float bf2f(short s) {
    unsigned u = ((unsigned)(unsigned short)s) << 16;
    float f;
    __builtin_memcpy(&f, &u, 4);
    return f;
}

// ---------------- prep: fold weights into d_ws (runs every call) ----------------
// ws layout (bytes):
//   0     : wkT  bf16 [64][64]  (W1b - W1c)^T   (row n, col k)
//   8192  : wdT  bf16 [64][64]  (W1d)^T
//   16384 : w2T  bf16 [32][64]  (W2)^T          (row o, col h)
//   20480 : wac  f32  [64][64]  W1a + W1c       (row i, col h)
__global__ void prep_fold(const float* __restrict__ W1, const float* __restrict__ W2,
                          void* __restrict__ ws)
{
    short* wkT = (short*)ws;
    short* wdT = wkT + 4096;
    short* w2T = wkT + 8192;
    float* wac = (float*)((char*)ws + 20480);
    const int tid = threadIdx.x;
    for (int idx = tid; idx < 4096; idx += 256) {
        int n = idx & 63, k = idx >> 6;
        float a  = W1[4096  + idx];   // W1b[k][n]
        float c  = W1[8192  + idx];   // W1c[k][n]
        float d  = W1[12288 + idx];   // W1d[k][n]
        wkT[n * 64 + k] = f2bf(a - c);
        wdT[n * 64 + k] = f2bf(d);
        wac[idx] = W1[idx] + c;       // elementwise: W1a + W1c (i-major)
    }
    for (int idx = tid; idx < 2048; idx += 256) {
        int o = idx & 31, h = idx >> 5;
        w2T[o * 64 + h] = f2bf(W2[idx]);   // W2[h][o], idx = h*32+o
    }
}

// ---------------- main: one block per batch ----------------
// Keys are read from HBM exactly once: bf16 A-fragments are kept in registers
// and reused for the softmax-weighted sum in the epilogue.
__global__ __launch_bounds__(256, 3) void attn_main(
    const float* __restrict__ query,    // (B,1,64)
    const float* __restrict__ keys,     // (B,200,64)
    const int*   __restrict__ keys_len, // (B,1)
    const float* __restrict__ b1,       // (64)
    const float* __restrict__ b2,       // (32)
    const float* __restrict__ W3,       // (32,1)
    const float* __restrict__ b3,       // (1)
    const void*  __restrict__ ws,
    float* __restrict__ out)            // (B,1,64)
{
    constexpr int STR = 72;   // shorts; 144 B row stride -> 16B-aligned b128 everywhere
    const short* wkT = (const short*)ws;
    const short* wdT = wkT + 4096;
    const short* w2T = wkT + 8192;
    const float* wac = (const float*)((const char*)ws + 20480);

    __shared__ short Bk[64 * STR];      // (W1b-W1c)^T
    __shared__ short Bd[64 * STR];      // W1d^T
    __shared__ short W2s[32 * STR];     // W2^T
    __shared__ short h1w[4][16 * STR];  // per-wave h1 tile (C-layout -> A-layout)
    __shared__ float qs[64], cs[64], b2s[32], w3s[32];
    __shared__ float s_arr[208], wsm[208];
    __shared__ float red[256];
    __shared__ float red4a[4], red4b[4];

    const int b    = blockIdx.x;
    const int tid  = threadIdx.x;
    const int lane = tid & 63;
    const int wid  = tid >> 6;
    const int col  = lane & 15;
    const int quad = lane >> 4;

    // ---- stage q + folded matrices (global, L2/L3-hot) ----
    if (tid < 16) ((float4*)qs)[tid] = ((const float4*)(query + (size_t)b * 64))[tid];
    for (int c = tid; c < 512; c += 256) {
        int r = c >> 3, ch = (c & 7) * 8;
        *(short8_t*)&Bk[r * STR + ch] = *(const short8_t*)(wkT + r * 64 + ch);
        *(short8_t*)&Bd[r * STR + ch] = *(const short8_t*)(wdT + r * 64 + ch);
    }
    {
        int r = tid >> 3, ch = (tid & 7) * 8;
        *(short8_t*)&W2s[r * STR + ch] = *(const short8_t*)(w2T + r * 64 + ch);
    }
    if (tid < 32) { b2s[tid] = b2[tid]; w3s[tid] = W3[tid]; }
    __syncthreads();   // qs + LDS matrices ready

    // ---- c_b partials: all 256 threads, 16 MACs each ----
    {
        int g = tid >> 6, h = tid & 63;
        float acc = 0.f;
#pragma unroll
        for (int j = 0; j < 16; ++j) {
            int i = g * 16 + j;
            acc += qs[i] * wac[i * 64 + h];
        }
        red[tid] = acc;
    }
    // per-lane q values for the (k*q) A-operand
    float4 qv[4];
#pragma unroll
    for (int ks = 0; ks < 2; ++ks) {
        qv[ks * 2]     = *(const float4*)&qs[ks * 32 + quad * 8];
        qv[ks * 2 + 1] = *(const float4*)&qs[ks * 32 + quad * 8 + 4];
    }
    __syncthreads();   // red ready
    if (tid < 64)
        cs[tid] = b1[tid] + red[tid] + red[64 + tid] + red[128 + tid] + red[192 + tid];
    __syncthreads();   // cs ready

    // ---- main wave loop: GEMM1 + fused GEMM2 -> s[t]; keep key frags in regs ----
    const float  b3v = b3[0];
    const float* kb  = keys + (size_t)b * 12800;
    short* hw = h1w[wid];
    const int nit = (wid == 0) ? 4 : 3;   // mt = wid, wid+4, wid+8 (,12 for wid 0)

    short8_t keep0[4], keep1[4];
    float4 n0, n1, n2, n3;
    {
        int row = wid * 16 + col;
        row = row < 200 ? row : 199;
        const float* kr = kb + row * 64 + quad * 8;
        n0 = *(const float4*)(kr);
        n1 = *(const float4*)(kr + 4);
        n2 = *(const float4*)(kr + 32);
        n3 = *(const float4*)(kr + 36);
    }

#pragma unroll
    for (int j = 0; j < 4; ++j) {
        if (j >= nit) break;              // wave-uniform
        const int mt = wid + j * 4;
        float4 k0 = n0, k1 = n1, k2 = n2, k3 = n3;
        if (j + 1 < nit) {                // prefetch next tile's rows
            int row = (mt + 4) * 16 + col;
            row = row < 200 ? row : 199;
            const float* kr = kb + row * 64 + quad * 8;
            n0 = *(const float4*)(kr);
            n1 = *(const float4*)(kr + 4);
            n2 = *(const float4*)(kr + 32);
            n3 = *(const float4*)(kr + 36);
        }

        short8_t aK0, aK1, aQ0, aQ1;
        aK0[0] = f2bf(k0.x); aK0[1] = f2bf(k0.y); aK0[2] = f2bf(k0.z); aK0[3] = f2bf(k0.w);
        aK0[4] = f2bf(k1.x); aK0[5] = f2bf(k1.y); aK0[6] = f2bf(k1.z); aK0[7] = f2bf(k1.w);
        aK1[0] = f2bf(k2.x); aK1[1] = f2bf(k2.y); aK1[2] = f2bf(k2.z); aK1[3] = f2bf(k2.w);
        aK1[4] = f2bf(k3.x); aK1[5] = f2bf(k3.y); aK1[6] = f2bf(k3.z); aK1[7] = f2bf(k3.w);
        aQ0[0] = f2bf(k0.x * qv[0].x); aQ0[1] = f2bf(k0.y * qv[0].y);
        aQ0[2] = f2bf(k0.z * qv[0].z); aQ0[3] = f2bf(k0.w * qv[0].w);
        aQ0[4] = f2bf(k1.x * qv[1].x); aQ0[5] = f2bf(k1.y * qv[1].y);
        aQ0[6] = f2bf(k1.z * qv[1].z); aQ0[7] = f2bf(k1.w * qv[1].w);
        aQ1[0] = f2bf(k2.x * qv[2].x); aQ1[1] = f2bf(k2.y * qv[2].y);
        aQ1[2] = f2bf(k2.z * qv[2].z); aQ1[3] = f2bf(k2.w * qv[2].w);
        aQ1[4] = f2bf(k3.x * qv[3].x); aQ1[5] = f2bf(k3.y * qv[3].y);
        aQ1[6] = f2bf(k3.z * qv[3].z); aQ1[7] = f2bf(k3.w * qv[3].w);
        keep0[j] = aK0;                  // retained for the weighted-sum epilogue
        keep1[j] = aK1;

        f32x4 acc[4] = {f32x4{0,0,0,0}, f32x4{0,0,0,0}, f32x4{0,0,0,0}, f32x4{0,0,0,0}};
#pragma unroll
        for (int nt = 0; nt < 4; ++nt) {
            const short* bp = &Bk[(nt * 16 + col) * STR + quad * 8];
            const short* dp = &Bd[(nt * 16 + col) * STR + quad * 8];
            acc[nt] = __builtin_amdgcn_mfma_f32_16x16x32_bf16(aK0, *(const short8_t*)bp,        acc[nt], 0, 0, 0);
            acc[nt] = __builtin_amdgcn_mfma_f32_16x16x32_bf16(aK1, *(const short8_t*)(bp + 32), acc[nt], 0, 0, 0);
            acc[nt] = __builtin_amdgcn_mfma_f32_16x16x32_bf16(aQ0, *(const short8_t*)dp,        acc[nt], 0, 0, 0);
            acc[nt] = __builtin_amdgcn_mfma_f32_16x16x32_bf16(aQ1, *(const short8_t*)(dp + 32), acc[nt], 0, 0, 0);
        }

        // relu + c -> per-wave h1 tile (intra-wave LDS, program-order safe)
#pragma unroll
        for (int nt = 0; nt < 4; ++nt) {
            float cadd = cs[nt * 16 + col];
#pragma unroll
            for (int r = 0; r < 4; ++r)
                hw[(quad * 4 + r) * STR + nt * 16 + col] = f2bf(fmaxf(acc[nt][r] + cadd, 0.f));
        }

        // GEMM2 (K=64) + fused b2/relu/W3/b3 -> s[t]
        f32x4 acc2[2] = {f32x4{0,0,0,0}, f32x4{0,0,0,0}};
#pragma unroll
        for (int ks = 0; ks < 2; ++ks) {
            short8_t a2 = *(const short8_t*)&hw[col * STR + ks * 32 + quad * 8];
            acc2[0] = __builtin_amdgcn_mfma_f32_16x16x32_bf16(
                a2, *(const short8_t*)&W2s[col * STR + ks * 32 + quad * 8], acc2[0], 0, 0, 0);
            acc2[1] = __builtin_amdgcn_mfma_f32_16x16x32_bf16(
                a2, *(const short8_t*)&W2s[(16 + col) * STR + ks * 32 + quad * 8], acc2[1], 0, 0, 0);
        }
#pragma unroll
        for (int r = 0; r < 4; ++r) {
            float v = fmaxf(acc2[0][r] + b2s[col], 0.f) * w3s[col]
                    + fmaxf(acc2[1][r] + b2s[16 + col], 0.f) * w3s[16 + col];
            v += __shfl_xor(v, 1);
            v += __shfl_xor(v, 2);
            v += __shfl_xor(v, 4);
            v += __shfl_xor(v, 8);
            if (col == 0) s_arr[mt * 16 + quad * 4 + r] = v + b3v;
        }
    }
    __syncthreads();

    // ---- masked softmax (len==0 -> uniform, matches reference) ----
    int len = keys_len[b];
    float val = (tid < 200) ? ((tid < len) ? s_arr[tid] : MASK_VAL) : -INFINITY;
    float m = val;
    for (int off = 32; off >= 1; off >>= 1) m = fmaxf(m, __shfl_xor(m, off));
    if (lane == 0) red4a[wid] = m;
    __syncthreads();
    m = fmaxf(fmaxf(red4a[0], red4a[1]), fmaxf(red4a[2], red4a[3]));
    float p = (tid < 200) ? __expf(val - m) : 0.0f;
    float ssum = p;
    for (int off = 32; off >= 1; off >>= 1) ssum += __shfl_xor(ssum, off);
    if (lane == 0) red4b[wid] = ssum;
    __syncthreads();
    float S = red4b[0] + red4b[1] + red4b[2] + red4b[3];
    if (tid < 200) wsm[tid] = p / S;
    __syncthreads();

    // ---- epilogue: out = w @ keys from the RETAINED register fragments ----
    {
        float accv[16];
#pragma unroll
        for (int i = 0; i < 16; ++i) accv[i] = 0.f;
#pragma unroll
        for (int j = 0; j < 4; ++j) {
            if (j >= nit) break;          // wave-uniform
            int row = (wid + j * 4) * 16 + col;
            float w = (row < 200) ? wsm[row] : 0.f;   // clamped tail rows get 0
            short8_t f0 = keep0[j], f1 = keep1[j];
#pragma unroll
            for (int i = 0; i < 8; ++i) {
                accv[i]     += w * bf2f(f0[i]);
                accv[8 + i] += w * bf2f(f1[i]);
            }
        }
        // reduce across the 16 col-lanes of each quad group
#pragma unroll
        for (int i = 0; i < 16; ++i) {
            float v = accv[i];
            v += __shfl_xor(v, 1);
            v += __shfl_xor(v, 2);
            v += __shfl_xor(v, 4);
            v += __shfl_xor(v, 8);
            accv[i] = v;
        }
        if (col == 0) {
#pragma unroll
            for (int i = 0; i < 8; ++i) {
                red[wid * 64 + quad * 8 + i]      = accv[i];
                red[wid * 64 + 32 + quad * 8 + i] = accv[8 + i];
            }
        }
        __syncthreads();
        if (tid < 64)
            out[(size_t)b * 64 + tid] = red[tid] + red[64 + tid] + red[128 + tid] + red[192 + tid];
    }
}

extern "C" void kernel_launch(void* const* d_in, const int* in_sizes, int n_in,
                              void* d_out, int out_size, void* d_ws, size_t ws_size,
                              hipStream_t stream) {
    const float* query    = (const float*)d_in[0];
    const float* keys     = (const float*)d_in[1];
    const int*   keys_len = (const int*)d_in[2];
    const float* W1       = (const float*)d_in[3];
    const float* b1       = (const float*)d_in[4];
    const float* W2       = (const float*)d_in[5];
    const float* b2       = (const float*)d_in[6];
    const float* W3       = (const float*)d_in[7];
    const float* b3       = (const float*)d_in[8];
    float* out            = (float*)d_out;

    const int B = in_sizes[1] / 12800;   // keys is (B,200,64)

    prep_fold<<<dim3(1), dim3(256), 0, stream>>>(W1, W2, d_ws);
    attn_main<<<dim3(B), dim3(256), 0, stream>>>(
        query, keys, keys_len, b1, b2, W3, b3, d_ws, out);
}